// Round 2
// baseline (183.646 us; speedup 1.0000x reference)
//
#include <hip/hip_runtime.h>
#include <math.h>

#define HH 96
#define WW 96
#define CC 64
#define BB 4
#define PLANE (HH * WW)          // 9216
#define NPLANES (BB * CC)        // 256
#define NPC (BB * PLANE)         // 36864 per-channel count
#define TILE 32
#define TPL 3
#define HALO 34
#define HALO_N (HALO * HALO)     // 1156
#define BLOCK 256
#define NBLK (TPL * NPLANES)     // 768 = exactly 3 blocks/CU x 256 CU

typedef _Float16 h2v __attribute__((ext_vector_type(2)));

static __device__ __forceinline__ float dot2h(unsigned a, unsigned b, float c) {
#if __has_builtin(__builtin_amdgcn_fdot2)
    return __builtin_amdgcn_fdot2(__builtin_bit_cast(h2v, a),
                                  __builtin_bit_cast(h2v, b), c, false);
#else
    h2v x = __builtin_bit_cast(h2v, a);
    h2v y = __builtin_bit_cast(h2v, b);
    return c + (float)x[0] * (float)y[0] + (float)x[1] * (float)y[1];
#endif
}

static __device__ __forceinline__ unsigned pk16(float a, float b) {
    return __builtin_bit_cast(unsigned, __builtin_amdgcn_cvt_pkrtz(a, b));
}

// Round-5: fused conv+BN+ReLU, single kernel, SOFTWARE grid barrier.
// (Round-4's hipLaunchCooperativeKernel silently failed to launch —
//  absmax == max|ref| meant all-zero output. Plain launch + spin barrier.)
// Co-residency: 45.4 KB LDS -> exactly 3 blocks/CU; grid 768 = 3*256.
// __launch_bounds__(256,3) pins VGPR<=168 so registers can't lower it.
// Barrier counter lives in ws at +8192B, zeroed by captured hipMemsetAsync.
// Spin is bounded (~11 ms) so a broken assumption fails, never hangs.

__global__ __launch_bounds__(BLOCK, 3) void kconv_fused(
    const float* __restrict__ x,
    const float* __restrict__ base_w,
    const float* __restrict__ spline_w,   // (9,8)
    const float* __restrict__ spline_s,   // (9,)
    const float* __restrict__ gamma,
    const float* __restrict__ beta,
    float* __restrict__ out,
    float2* __restrict__ part,
    unsigned* __restrict__ bar)
{
    __shared__ uint4  s_n[2][HALO_N];
    __shared__ float  s_sl[2][HALO_N];
    __shared__ unsigned s_wp[36];
    __shared__ float  s_bw[9];
    __shared__ float2 red[4];
    __shared__ float2 sb;

    const int tid = threadIdx.x;

    if (tid < 36) {
        const int j = tid >> 2;
        const int k = tid & 3;
        const float sc = spline_s[j];
        s_wp[tid] = pk16(spline_w[j * 8 + 2 * k] * sc,
                         spline_w[j * 8 + 2 * k + 1] * sc);
    }
    if (tid < 9) s_bw[tid] = base_w[tid];

    const int plane = blockIdx.y;
    const int h0 = blockIdx.x * TILE;
    const float* xp = x + (size_t)plane * PLANE;

    int hy[5], hx[5];
#pragma unroll
    for (int s = 0; s < 5; ++s) {
        const int i = tid + s * BLOCK;
        const int r = i / HALO;
        hy[s] = r;
        hx[s] = i - r * HALO;
    }

    const int tx  = tid & 31;
    const int ty4 = (tid >> 5) * 4;

    float lsum = 0.0f, lsq = 0.0f;
    float accAll[TPL][4];

    // ---- phase A+B for tile 0 into buf 0 ----
    float v[5];
#pragma unroll
    for (int s = 0; s < 5; ++s) {
        const int gh = h0 + hy[s] - 1;
        const int gw = hx[s] - 1;                 // w0 = 0
        const bool ok = (tid + s * BLOCK < HALO_N) &&
                        gh >= 0 && gh < HH && gw >= 0 && gw < WW;
        v[s] = ok ? xp[gh * WW + gw] : 0.0f;
    }
#pragma unroll
    for (int s = 0; s < 5; ++s) {
        const int i = tid + s * BLOCK;
        if (i >= HALO_N) break;
        const float vv = v[s];
        const float e  = __expf(-vv);
        const float sl = vv * __builtin_amdgcn_rcpf(1.0f + e);
        const float sp = fmaf(vv, 2.5f, 2.5f);
        const float tf = floorf(sp);
        const float u  = sp - tf;
        const int   t  = (int)tf;
        const int   m  = t >> 1;
        const bool  odd = (t & 1) != 0;
        const float w1m = 1.0f - u;
        const float u2 = u * u;
        const float u3 = u2 * u;
        const float B0 = w1m * w1m * (w1m * (1.0f / 6.0f));
        const float B3 = u2 * (u * (1.0f / 6.0f));
        const float B1 = fmaf(-u2, 1.0f, fmaf(u3, 0.5f, 2.0f / 3.0f));
        const float B2 = 1.0f - B0 - B1 - B3;
        const unsigned h01 = pk16(B0, B1);
        const unsigned h23 = pk16(B2, B3);
        unsigned n[4];
        unsigned a_prev;
        {
            const int k0 = -1 - m;
            a_prev = (k0 == 0) ? h01 : ((k0 == 1) ? h23 : 0u);
        }
#pragma unroll
        for (int d = 0; d < 4; ++d) {
            const int k0 = d - m;
            const unsigned a_cur = (k0 == 0) ? h01 : ((k0 == 1) ? h23 : 0u);
            const unsigned sh = __builtin_amdgcn_alignbit(a_cur, a_prev, 16);
            n[d] = odd ? sh : a_cur;
            a_prev = a_cur;
        }
        s_n[0][i]  = make_uint4(n[0], n[1], n[2], n[3]);
        s_sl[0][i] = sl;
    }
    __syncthreads();                              // weights + buf0 visible

    unsigned wp[36];
    float bw[9];
#pragma unroll
    for (int q = 0; q < 36; ++q)
        wp[q] = __builtin_amdgcn_readfirstlane(s_wp[q]);
#pragma unroll
    for (int q = 0; q < 9; ++q)
        bw[q] = __int_as_float(__builtin_amdgcn_readfirstlane(__float_as_int(s_bw[q])));

#pragma unroll
    for (int wt = 0; wt < TPL; ++wt) {
        const int cur = wt & 1;
        const int nxt = cur ^ 1;

        // ---- phase A for tile wt+1 (independent; lands during phase C) ----
        if (wt < TPL - 1) {
            const int w0n = (wt + 1) * TILE;
#pragma unroll
            for (int s = 0; s < 5; ++s) {
                const int gh = h0 + hy[s] - 1;
                const int gw = w0n + hx[s] - 1;
                const bool ok = (tid + s * BLOCK < HALO_N) &&
                                gh >= 0 && gh < HH && gw >= 0 && gw < WW;
                v[s] = ok ? xp[gh * WW + gw] : 0.0f;
            }
        }

        // ---- phase C: consume buf[cur] ----
        float acc[4] = {0.0f, 0.0f, 0.0f, 0.0f};
#pragma unroll
        for (int r = 0; r < 6; ++r) {
            const int base = (ty4 + r) * HALO + tx;
            uint4 cn[3];
            float cs[3];
#pragma unroll
            for (int dw = 0; dw < 3; ++dw) {
                cn[dw] = s_n[cur][base + dw];
                cs[dw] = s_sl[cur][base + dw];
            }
#pragma unroll
            for (int k = 0; k < 4; ++k) {
                const int dh = r - k;
                if (dh >= 0 && dh < 3) {
                    float a = acc[k];
#pragma unroll
                    for (int dw = 0; dw < 3; ++dw) {
                        const int j = dh * 3 + dw;
                        a = dot2h(cn[dw].x, wp[j * 4 + 0], a);
                        a = dot2h(cn[dw].y, wp[j * 4 + 1], a);
                        a = dot2h(cn[dw].z, wp[j * 4 + 2], a);
                        a = dot2h(cn[dw].w, wp[j * 4 + 3], a);
                        a = fmaf(bw[j], cs[dw], a);
                    }
                    acc[k] = a;
                }
            }
        }

        // stats for this tile; outputs stay in registers
#pragma unroll
        for (int k = 0; k < 4; ++k) {
            accAll[wt][k] = acc[k];
            lsum += acc[k];
            lsq = fmaf(acc[k], acc[k], lsq);
        }

        // ---- phase B: build buf[nxt] from prefetched v ----
        if (wt < TPL - 1) {
#pragma unroll
            for (int s = 0; s < 5; ++s) {
                const int i = tid + s * BLOCK;
                if (i >= HALO_N) break;
                const float vv = v[s];
                const float e  = __expf(-vv);
                const float sl = vv * __builtin_amdgcn_rcpf(1.0f + e);
                const float sp = fmaf(vv, 2.5f, 2.5f);
                const float tf = floorf(sp);
                const float u  = sp - tf;
                const int   t  = (int)tf;
                const int   m  = t >> 1;
                const bool  odd = (t & 1) != 0;
                const float w1m = 1.0f - u;
                const float u2 = u * u;
                const float u3 = u2 * u;
                const float B0 = w1m * w1m * (w1m * (1.0f / 6.0f));
                const float B3 = u2 * (u * (1.0f / 6.0f));
                const float B1 = fmaf(-u2, 1.0f, fmaf(u3, 0.5f, 2.0f / 3.0f));
                const float B2 = 1.0f - B0 - B1 - B3;
                const unsigned h01 = pk16(B0, B1);
                const unsigned h23 = pk16(B2, B3);
                unsigned n[4];
                unsigned a_prev;
                {
                    const int k0 = -1 - m;
                    a_prev = (k0 == 0) ? h01 : ((k0 == 1) ? h23 : 0u);
                }
#pragma unroll
                for (int d = 0; d < 4; ++d) {
                    const int k0 = d - m;
                    const unsigned a_cur = (k0 == 0) ? h01 : ((k0 == 1) ? h23 : 0u);
                    const unsigned sh = __builtin_amdgcn_alignbit(a_cur, a_prev, 16);
                    n[d] = odd ? sh : a_cur;
                    a_prev = a_cur;
                }
                s_n[nxt][i]  = make_uint4(n[0], n[1], n[2], n[3]);
                s_sl[nxt][i] = sl;
            }
            __syncthreads();                      // one barrier per tile
        }
    }

    // ---- block reduction of (sum, sumsq) -> part[plane*3 + strip] ----
#pragma unroll
    for (int off = 32; off; off >>= 1) {
        lsum += __shfl_down(lsum, off, 64);
        lsq  += __shfl_down(lsq,  off, 64);
    }
    if ((tid & 63) == 0) red[tid >> 6] = make_float2(lsum, lsq);
    __syncthreads();

    // ---- software grid barrier (bounded spin; never hangs) ----
    if (tid == 0) {
        const float s = red[0].x + red[1].x + red[2].x + red[3].x;
        const float q = red[0].y + red[1].y + red[2].y + red[3].y;
        const float2 pv = make_float2(s, q);
        __hip_atomic_store((unsigned long long*)&part[plane * TPL + blockIdx.x],
                           __builtin_bit_cast(unsigned long long, pv),
                           __ATOMIC_RELAXED, __HIP_MEMORY_SCOPE_AGENT);
        // arrival: release orders the part store before the count bump
        __hip_atomic_fetch_add(bar, 1u, __ATOMIC_RELEASE,
                               __HIP_MEMORY_SCOPE_AGENT);
        int spins = 0;
        while (__hip_atomic_load(bar, __ATOMIC_ACQUIRE,
                                 __HIP_MEMORY_SCOPE_AGENT) < (unsigned)NBLK) {
            __builtin_amdgcn_s_sleep(1);
            if (++spins > (1 << 18)) break;       // ~11 ms bound: fail, don't hang
        }
    }
    __syncthreads();                              // all threads see barrier done

    // ---- per-channel stats (each block redundantly reduces its channel) ----
    const int c = plane & (CC - 1);
    if (tid < 64) {
        float s = 0.0f, q = 0.0f;
        if (tid < 12) {                   // 4 batches x 3 strips
            const int b = tid / 3;
            const int t = tid - b * 3;
            const unsigned long long pv = __hip_atomic_load(
                (const unsigned long long*)&part[(c + CC * b) * TPL + t],
                __ATOMIC_ACQUIRE, __HIP_MEMORY_SCOPE_AGENT);
            const float2 pp = __builtin_bit_cast(float2, pv);
            s = pp.x; q = pp.y;
        }
#pragma unroll
        for (int off = 8; off; off >>= 1) {
            s += __shfl_down(s, off, 64);
            q += __shfl_down(q, off, 64);
        }
        if (tid == 0) {
            const float inv  = 1.0f / (float)NPC;
            const float mean = s * inv;
            const float var  = q * inv - mean * mean;
            const float sc   = rsqrtf(var + 1e-5f) * gamma[c];
            sb = make_float2(sc, beta[c] - mean * sc);
        }
    }
    __syncthreads();
    const float2 sbv = sb;

    // ---- normalize in-register conv outputs, write final output once ----
    float* yp = out + (size_t)plane * PLANE + (size_t)h0 * WW;
#pragma unroll
    for (int wt = 0; wt < TPL; ++wt) {
#pragma unroll
        for (int k = 0; k < 4; ++k) {
            yp[(ty4 + k) * WW + wt * TILE + tx] =
                fmaxf(fmaf(accAll[wt][k], sbv.x, sbv.y), 0.0f);
        }
    }
}

extern "C" void kernel_launch(void* const* d_in, const int* in_sizes, int n_in,
                              void* d_out, int out_size, void* d_ws, size_t ws_size,
                              hipStream_t stream)
{
    const float* x        = (const float*)d_in[0];
    const float* base_w   = (const float*)d_in[1];
    const float* spline_w = (const float*)d_in[2];
    const float* spline_s = (const float*)d_in[3];
    const float* gamma    = (const float*)d_in[4];
    const float* beta     = (const float*)d_in[5];
    float* out   = (float*)d_out;
    float2* part = (float2*)d_ws;
    unsigned* bar = (unsigned*)((char*)d_ws + 8192);

    // zero the barrier counter (workspace is poisoned between iterations);
    // async memset is graph-capturable (the harness uses the same path).
    hipMemsetAsync(bar, 0, 16, stream);

    dim3 g1(TPL, NPLANES);   // 768 blocks = exactly 3/CU (45.4 KB LDS)
    kconv_fused<<<g1, BLOCK, 0, stream>>>(x, base_w, spline_w, spline_s,
                                          gamma, beta, out, part, bar);
}

// Round 3
// 86.827 us; speedup vs baseline: 2.1151x; 2.1151x over previous
//
#include <hip/hip_runtime.h>
#include <math.h>

#define HH 96
#define WW 96
#define CC 64
#define BB 4
#define PLANE (HH * WW)          // 9216
#define NPLANES (BB * CC)        // 256
#define NPC (BB * PLANE)         // 36864 per-channel count
#define TILE 32
#define TPT 3                    // tiles per row/col
#define NTILES (TPT * TPT)       // 9 tiles per plane
#define HALO 34
#define HALO_N (HALO * HALO)     // 1156
#define BLOCK 256

typedef _Float16 h2v __attribute__((ext_vector_type(2)));

static __device__ __forceinline__ float dot2h(unsigned a, unsigned b, float c) {
#if __has_builtin(__builtin_amdgcn_fdot2)
    return __builtin_amdgcn_fdot2(__builtin_bit_cast(h2v, a),
                                  __builtin_bit_cast(h2v, b), c, false);
#else
    h2v x = __builtin_bit_cast(h2v, a);
    h2v y = __builtin_bit_cast(h2v, b);
    return c + (float)x[0] * (float)y[0] + (float)x[1] * (float)y[1];
#endif
}

static __device__ __forceinline__ unsigned pk16(float a, float b) {
    return __builtin_bit_cast(unsigned, __builtin_amdgcn_cvt_pkrtz(a, b));
}

// Round-6: revert the grid-barrier fusion (2x regression: spills + global
// serialization). Two kernels again, but stage1 restructured for OCCUPANCY:
// one 32x32 tile per block, SINGLE 23.2 KB LDS buffer -> 6 blocks/CU
// (24 waves/CU, was 3 blocks/46.5 KB double-buffer). Grid 2304 blocks =
// 9 waves of work per CU; inter-block overlap replaces the old intra-block
// double-buffer pipeline. Same total x fetch (9 halos/plane), same math,
// verified op order from the 85.6 us round-3 kernel.

__global__ __launch_bounds__(BLOCK) void kconv_stage1(
    const float* __restrict__ x,
    const float* __restrict__ base_w,
    const float* __restrict__ spline_w,   // (9,8)
    const float* __restrict__ spline_s,   // (9,)
    float* __restrict__ y,
    float2* __restrict__ part)
{
    __shared__ uint4  s_n[HALO_N];
    __shared__ float  s_sl[HALO_N];
    __shared__ unsigned s_wp[36];
    __shared__ float  s_bw[9];
    __shared__ float2 red[4];

    const int tid = threadIdx.x;

    if (tid < 36) {
        const int j = tid >> 2;
        const int k = tid & 3;
        const float sc = spline_s[j];
        s_wp[tid] = pk16(spline_w[j * 8 + 2 * k] * sc,
                         spline_w[j * 8 + 2 * k + 1] * sc);
    }
    if (tid < 9) s_bw[tid] = base_w[tid];

    const int plane = blockIdx.y;
    const int t  = blockIdx.x;            // 0..8
    const int r0 = (t / TPT) * TILE;
    const int c0 = (t - (t / TPT) * TPT) * TILE;
    const float* xp = x + (size_t)plane * PLANE;

    // ---- phase A: global halo load (issued before anything depends on it) ----
    int hy[5], hx[5];
    float v[5];
#pragma unroll
    for (int s = 0; s < 5; ++s) {
        const int i = tid + s * BLOCK;
        const int r = i / HALO;
        hy[s] = r;
        hx[s] = i - r * HALO;
    }
#pragma unroll
    for (int s = 0; s < 5; ++s) {
        const int gh = r0 + hy[s] - 1;
        const int gw = c0 + hx[s] - 1;
        const bool ok = (tid + s * BLOCK < HALO_N) &&
                        gh >= 0 && gh < HH && gw >= 0 && gw < WW;
        v[s] = ok ? xp[gh * WW + gw] : 0.0f;
    }

    // ---- phase B: silu + spline bases -> packed LDS ----
#pragma unroll
    for (int s = 0; s < 5; ++s) {
        const int i = tid + s * BLOCK;
        if (i >= HALO_N) break;
        const float vv = v[s];
        const float e  = __expf(-vv);
        const float sl = vv * __builtin_amdgcn_rcpf(1.0f + e);
        const float sp = fmaf(vv, 2.5f, 2.5f);
        const float tf = floorf(sp);
        const float u  = sp - tf;
        const int   tt = (int)tf;
        const int   m  = tt >> 1;
        const bool  odd = (tt & 1) != 0;
        const float w1m = 1.0f - u;
        const float u2 = u * u;
        const float u3 = u2 * u;
        const float B0 = w1m * w1m * (w1m * (1.0f / 6.0f));
        const float B3 = u2 * (u * (1.0f / 6.0f));
        const float B1 = fmaf(-u2, 1.0f, fmaf(u3, 0.5f, 2.0f / 3.0f));
        const float B2 = 1.0f - B0 - B1 - B3;
        const unsigned h01 = pk16(B0, B1);
        const unsigned h23 = pk16(B2, B3);
        unsigned n[4];
        unsigned a_prev;
        {
            const int k0 = -1 - m;
            a_prev = (k0 == 0) ? h01 : ((k0 == 1) ? h23 : 0u);
        }
#pragma unroll
        for (int d = 0; d < 4; ++d) {
            const int k0 = d - m;
            const unsigned a_cur = (k0 == 0) ? h01 : ((k0 == 1) ? h23 : 0u);
            const unsigned sh = __builtin_amdgcn_alignbit(a_cur, a_prev, 16);
            n[d] = odd ? sh : a_cur;
            a_prev = a_cur;
        }
        s_n[i]  = make_uint4(n[0], n[1], n[2], n[3]);
        s_sl[i] = sl;
    }
    __syncthreads();                              // weights + halo visible

    unsigned wp[36];
    float bw[9];
#pragma unroll
    for (int q = 0; q < 36; ++q)
        wp[q] = __builtin_amdgcn_readfirstlane(s_wp[q]);
#pragma unroll
    for (int q = 0; q < 9; ++q)
        bw[q] = __int_as_float(__builtin_amdgcn_readfirstlane(__float_as_int(s_bw[q])));

    const int tx  = tid & 31;
    const int ty4 = (tid >> 5) * 4;

    // ---- phase C: consume LDS, 4 output rows per thread ----
    float acc[4] = {0.0f, 0.0f, 0.0f, 0.0f};
#pragma unroll
    for (int r = 0; r < 6; ++r) {
        const int base = (ty4 + r) * HALO + tx;
        uint4 cn[3];
        float cs[3];
#pragma unroll
        for (int dw = 0; dw < 3; ++dw) {
            cn[dw] = s_n[base + dw];
            cs[dw] = s_sl[base + dw];
        }
#pragma unroll
        for (int k = 0; k < 4; ++k) {
            const int dh = r - k;
            if (dh >= 0 && dh < 3) {
                float a = acc[k];
#pragma unroll
                for (int dw = 0; dw < 3; ++dw) {
                    const int j = dh * 3 + dw;
                    a = dot2h(cn[dw].x, wp[j * 4 + 0], a);
                    a = dot2h(cn[dw].y, wp[j * 4 + 1], a);
                    a = dot2h(cn[dw].z, wp[j * 4 + 2], a);
                    a = dot2h(cn[dw].w, wp[j * 4 + 3], a);
                    a = fmaf(bw[j], cs[dw], a);
                }
                acc[k] = a;
            }
        }
    }

    // y write + stats
    float lsum = 0.0f, lsq = 0.0f;
    float* yp = y + (size_t)plane * PLANE + (size_t)r0 * WW + c0;
#pragma unroll
    for (int k = 0; k < 4; ++k) {
        yp[(ty4 + k) * WW + tx] = acc[k];
        lsum += acc[k];
        lsq = fmaf(acc[k], acc[k], lsq);
    }

#pragma unroll
    for (int off = 32; off; off >>= 1) {
        lsum += __shfl_down(lsum, off, 64);
        lsq  += __shfl_down(lsq,  off, 64);
    }
    if ((tid & 63) == 0) red[tid >> 6] = make_float2(lsum, lsq);
    __syncthreads();
    if (tid == 0) {
        const float s = red[0].x + red[1].x + red[2].x + red[3].x;
        const float q = red[0].y + red[1].y + red[2].y + red[3].y;
        part[plane * NTILES + t] = make_float2(s, q);
    }
}

__global__ __launch_bounds__(BLOCK) void kconv_stage2(
    float* __restrict__ y,
    const float2* __restrict__ part,
    const float* __restrict__ gamma,
    const float* __restrict__ beta)
{
    __shared__ float2 sb;
    const int tid = threadIdx.x;
    const int plane = blockIdx.x;
    const int c = plane & (CC - 1);

    if (tid < 64) {
        float s = 0.0f, q = 0.0f;
        if (tid < 36) {                   // 4 batches x 9 tiles
            const int b = tid / 9;
            const int t = tid - b * 9;
            const float2 pp = part[(c + CC * b) * NTILES + t];
            s = pp.x; q = pp.y;
        }
#pragma unroll
        for (int off = 32; off; off >>= 1) {
            s += __shfl_down(s, off, 64);
            q += __shfl_down(q, off, 64);
        }
        if (tid == 0) {
            const float inv = 1.0f / (float)NPC;
            const float mean = s * inv;
            const float var  = q * inv - mean * mean;
            const float sc   = rsqrtf(var + 1e-5f) * gamma[c];
            sb = make_float2(sc, beta[c] - mean * sc);
        }
    }
    __syncthreads();
    const float2 sbv = sb;

    float4* yp = (float4*)(y + (size_t)plane * PLANE + (size_t)blockIdx.y * 1024);
    float4 v = yp[tid];
    v.x = fmaxf(fmaf(v.x, sbv.x, sbv.y), 0.0f);
    v.y = fmaxf(fmaf(v.y, sbv.x, sbv.y), 0.0f);
    v.z = fmaxf(fmaf(v.z, sbv.x, sbv.y), 0.0f);
    v.w = fmaxf(fmaf(v.w, sbv.x, sbv.y), 0.0f);
    yp[tid] = v;
}

extern "C" void kernel_launch(void* const* d_in, const int* in_sizes, int n_in,
                              void* d_out, int out_size, void* d_ws, size_t ws_size,
                              hipStream_t stream)
{
    const float* x        = (const float*)d_in[0];
    const float* base_w   = (const float*)d_in[1];
    const float* spline_w = (const float*)d_in[2];
    const float* spline_s = (const float*)d_in[3];
    const float* gamma    = (const float*)d_in[4];
    const float* beta     = (const float*)d_in[5];
    float* out   = (float*)d_out;
    float2* part = (float2*)d_ws;

    dim3 g1(NTILES, NPLANES);   // 2304 blocks, 23.2 KB LDS -> 6 blocks/CU
    kconv_stage1<<<g1, BLOCK, 0, stream>>>(x, base_w, spline_w, spline_s, out, part);

    dim3 g2(NPLANES, PLANE / (BLOCK * 4));
    kconv_stage2<<<g2, BLOCK, 0, stream>>>(out, part, gamma, beta);
}